// Round 16
// baseline (262.927 us; speedup 1.0000x reference)
//
#include <hip/hip_runtime.h>
#include <hip/hip_bf16.h>

#define B_ 8
#define T_ 2048
#define C_ 400
#define H_ 4
#define D_ 100
#define DP 128
#define KP 416   // C_ padded to 13*32
#define KPB 832  // KP bytes (bf16)
// Q prescale: 1/sqrt(100) * log2(e)  (softmax runs in exp2 domain)
#define QSCALE 0.14426950408889634f
// static softmax shift (shift-invariant; >=9-sigma bound on log2-domain scores)
#define MSTATIC 16.0f

typedef __hip_bfloat16 bf16;
typedef unsigned int uint32;
typedef __attribute__((ext_vector_type(8))) short short8;
typedef __attribute__((ext_vector_type(4))) float f32x4;

__device__ __forceinline__ float bf2f(bf16 v){ return __bfloat162float(v); }
__device__ __forceinline__ bf16 f2bf(float f){ return __float2bfloat16(f); }
__device__ __forceinline__ unsigned short bfbits(float f){
  bf16 h = f2bf(f);
  return __builtin_bit_cast(unsigned short, h);
}
__device__ __forceinline__ uint32 pk2(float a, float b){
  return (uint32)bfbits(a) | ((uint32)bfbits(b) << 16);
}
__device__ __forceinline__ void gl_lds16(const char* gsrc, char* ldst){
  __builtin_amdgcn_global_load_lds(
      (const __attribute__((address_space(1))) unsigned int*)gsrc,
      (__attribute__((address_space(3))) unsigned int*)ldst, 16, 0, 0);
}

// ---------------------------------------------------------------------------
// Merged cold prep (one launch):
//  [0, 16384*52)          : x fp32 -> xb bf16 [16384][416], pad cols zero
//  [.., +12*128*416)      : WT [12][128][416] = Wq/Wk/Wv transposed, padded
//  [.., +512*416)         : WoB [512][416] = Wo rows (W^T layout), padded
__global__ __launch_bounds__(256) void prep_all_kernel(const float* __restrict__ x,
    const float* __restrict__ Wq, const float* __restrict__ Wk,
    const float* __restrict__ Wv, const float* __restrict__ Wo,
    bf16* __restrict__ xb, bf16* __restrict__ WT, bf16* __restrict__ WoB){
  int i = blockIdx.x*256 + threadIdx.x;
  if (i < 16384*52){
    int c8 = i % 52, t = i / 52;
    uint32 u[4];
    if (c8 < 50){
      const float* src = x + (size_t)t*C_ + c8*8;
      #pragma unroll
      for (int k=0;k<4;++k) u[k] = pk2(src[2*k], src[2*k+1]);
    } else {
      u[0]=u[1]=u[2]=u[3]=0;
    }
    *reinterpret_cast<uint4*>((char*)xb + (size_t)t*KPB + c8*16) = make_uint4(u[0],u[1],u[2],u[3]);
    return;
  }
  i -= 16384*52;
  if (i < 12*128*KP){
    int c = i % KP, n = (i/KP) & 127, group = i/(KP*128);
    int p = group >> 2, h = group & 3;
    float v = 0.f;
    if (n < D_ && c < C_){
      const float* W = (p==0)?Wq:(p==1)?Wk:Wv;
      v = W[((size_t)h*C_ + c)*D_ + n];
    }
    WT[i] = f2bf(v);
    return;
  }
  i -= 12*128*KP;
  if (i < 512*KP){
    int c = i % KP, n = i / KP;
    float v = (n < C_ && c < C_) ? Wo[(size_t)n*C_ + c] : 0.f;
    WoB[i] = f2bf(v);
  }
}

// ---------------------------------------------------------------------------
// QKV MFMA GEMM v2: 2 head-groups per block (pair never crosses p), sharing
// the x-tile stages: per K-step 6 stage-issues serve 2x output (-25% staging),
// af LDS reads shared. Grid 768. Q stores pre-scaled by QSCALE.
__global__ __launch_bounds__(256) void qkv_gemm_kernel(const bf16* __restrict__ xb,
    const bf16* __restrict__ WT, bf16* __restrict__ Qp, bf16* __restrict__ Kp,
    bf16* __restrict__ VT){
  __shared__ __align__(16) char xs[2][8192];
  __shared__ __align__(16) char wsh[2][2][8192];     // [buf][grp]
  int bid = blockIdx.x;
  int xcd = bid & 7, idx = bid >> 3;             // idx 0..95
  int mb = xcd*16 + idx/6;
  int gpair = idx % 6;
  int group0 = gpair*2;
  int p = group0 >> 2;                           // uniform for the pair
  int t0 = mb * 128;
  int tid = threadIdx.x;
  int w = tid >> 6, l = tid & 63, g = l >> 4, qi = l & 15;
  const char* xg = (const char*)xb + (size_t)t0*KPB;
  const char* wg0 = (const char*)WT + (size_t)group0*128*KPB;
  const char* wg1 = wg0 + (size_t)128*KPB;
  int srow = tid >> 2, sseg = tid & 3;

  #define GSTAGE(J, BUF) {                                                     \
    int kc2 = (J)*64;                                                          \
    _Pragma("unroll")                                                          \
    for (int r2=0;r2<2;++r2)                                                   \
      gl_lds16(xg + (size_t)(srow + r2*64)*KPB + kc2 + sseg*16,                \
               &xs[BUF][tid*16 + r2*4096]);                                    \
    _Pragma("unroll")                                                          \
    for (int r2=0;r2<2;++r2)                                                   \
      gl_lds16(wg0 + (size_t)(srow + r2*64)*KPB + kc2 + sseg*16,               \
               &wsh[BUF][0][tid*16 + r2*4096]);                                \
    _Pragma("unroll")                                                          \
    for (int r2=0;r2<2;++r2)                                                   \
      gl_lds16(wg1 + (size_t)(srow + r2*64)*KPB + kc2 + sseg*16,               \
               &wsh[BUF][1][tid*16 + r2*4096]); }

  f32x4 acc[2][2][8];                            // [grp][mt][nt]
  #pragma unroll
  for (int gr=0;gr<2;++gr)
    #pragma unroll
    for (int mt=0;mt<2;++mt)
      #pragma unroll
      for (int nt=0;nt<8;++nt) acc[gr][mt][nt] = (f32x4){0.f,0.f,0.f,0.f};

  GSTAGE(0, 0)
  __syncthreads();
  for (int j = 0; j < 13; ++j){
    int cur = j & 1;
    if (j < 12) GSTAGE(j+1, cur^1)
    short8 af[2];
    #pragma unroll
    for (int mt=0;mt<2;++mt)
      af[mt] = *reinterpret_cast<const short8*>(&xs[cur][(w*32 + mt*16 + qi)*64 + g*16]);
    #pragma unroll
    for (int gr=0;gr<2;++gr){
      short8 bfr[8];
      #pragma unroll
      for (int nt=0;nt<8;++nt)
        bfr[nt] = *reinterpret_cast<const short8*>(&wsh[cur][gr][(nt*16 + qi)*64 + g*16]);
      if (p < 2){
        #pragma unroll
        for (int mt=0;mt<2;++mt)
          #pragma unroll
          for (int nt=0;nt<8;++nt)
            acc[gr][mt][nt] = __builtin_amdgcn_mfma_f32_16x16x32_bf16(af[mt], bfr[nt], acc[gr][mt][nt], 0,0,0);
      } else {
        #pragma unroll
        for (int mt=0;mt<2;++mt)
          #pragma unroll
          for (int nt=0;nt<8;++nt)
            acc[gr][mt][nt] = __builtin_amdgcn_mfma_f32_16x16x32_bf16(bfr[nt], af[mt], acc[gr][mt][nt], 0,0,0);
      }
    }
    __syncthreads();
  }

  int b = t0 >> 11, tloc0 = t0 & 2047;
  #pragma unroll
  for (int gr=0;gr<2;++gr){
    int h = (group0 + gr) & 3;
    size_t bh = (size_t)b*H_ + h;
    if (p < 2){
      float qs = (p==0) ? QSCALE : 1.0f;
      bf16* dst = (p==0 ? Qp : Kp) + (bh*T_ + tloc0)*DP;
      #pragma unroll
      for (int mt=0;mt<2;++mt)
        #pragma unroll
        for (int r=0;r<4;++r){
          int tr = w*32 + mt*16 + 4*g + r;
          #pragma unroll
          for (int nt=0;nt<8;++nt)
            dst[(size_t)tr*DP + nt*16 + qi] = f2bf(qs * acc[gr][mt][nt][r]);
        }
    } else {
      bf16* dstv = VT + bh*DP*T_ + tloc0;
      #pragma unroll
      for (int nt=0;nt<8;++nt)
        #pragma unroll
        for (int r=0;r<4;++r){
          int d = nt*16 + 4*g + r;
          #pragma unroll
          for (int mt=0;mt<2;++mt)
            dstv[(size_t)d*T_ + w*32 + mt*16 + qi] = f2bf(acc[gr][mt][nt][r]);
        }
    }
  }
  #undef GSTAGE
}

// ---------------------------------------------------------------------------
// Out-proj MFMA GEMM (unchanged).
__global__ __launch_bounds__(256) void out_gemm_kernel(const bf16* __restrict__ AOb,
    const bf16* __restrict__ WoB, const float* __restrict__ bo, float* __restrict__ out){
  __shared__ __align__(16) char xs[2][8192];
  __shared__ __align__(16) char wsh[2][8192];
  int bid = blockIdx.x;
  int xcd = bid & 7, idx = bid >> 3;             // idx 0..63
  int mb = xcd*16 + idx/4;
  int nb = idx & 3;
  int t0 = mb * 128, n0 = nb * 128;
  int tid = threadIdx.x;
  int w = tid >> 6, l = tid & 63, g = l >> 4, qi = l & 15;
  const char* xg = (const char*)AOb + (size_t)t0*KPB;
  const char* wg = (const char*)WoB + (size_t)n0*KPB;
  int srow = tid >> 2, sseg = tid & 3;

  #define GSTAGE(J, BUF) {                                                     \
    int kc2 = (J)*64;                                                          \
    _Pragma("unroll")                                                          \
    for (int r2=0;r2<2;++r2)                                                   \
      gl_lds16(xg + (size_t)(srow + r2*64)*KPB + kc2 + sseg*16,                \
               &xs[BUF][tid*16 + r2*4096]);                                    \
    _Pragma("unroll")                                                          \
    for (int r2=0;r2<2;++r2)                                                   \
      gl_lds16(wg + (size_t)(srow + r2*64)*KPB + kc2 + sseg*16,                \
               &wsh[BUF][tid*16 + r2*4096]); }

  f32x4 acc[2][8];
  #pragma unroll
  for (int mt=0;mt<2;++mt)
    #pragma unroll
    for (int nt=0;nt<8;++nt) acc[mt][nt] = (f32x4){0.f,0.f,0.f,0.f};

  GSTAGE(0, 0)
  __syncthreads();
  for (int j = 0; j < 13; ++j){
    int cur = j & 1;
    if (j < 12) GSTAGE(j+1, cur^1)
    short8 af[2];
    #pragma unroll
    for (int mt=0;mt<2;++mt)
      af[mt] = *reinterpret_cast<const short8*>(&xs[cur][(w*32 + mt*16 + qi)*64 + g*16]);
    short8 bfr[8];
    #pragma unroll
    for (int nt=0;nt<8;++nt)
      bfr[nt] = *reinterpret_cast<const short8*>(&wsh[cur][(nt*16 + qi)*64 + g*16]);
    #pragma unroll
    for (int mt=0;mt<2;++mt)
      #pragma unroll
      for (int nt=0;nt<8;++nt)
        acc[mt][nt] = __builtin_amdgcn_mfma_f32_16x16x32_bf16(af[mt], bfr[nt], acc[mt][nt], 0,0,0);
    __syncthreads();
  }

  #pragma unroll
  for (int nt=0;nt<8;++nt){
    if (n0 + nt*16 >= C_) continue;              // wave-uniform (400 % 16 == 0)
    int n = n0 + nt*16 + qi;
    float bv = bo[n];
    #pragma unroll
    for (int mt=0;mt<2;++mt)
      #pragma unroll
      for (int r=0;r<4;++r){
        int tr = w*32 + mt*16 + 4*g + r;
        out[(size_t)(t0 + tr)*C_ + n] = acc[mt][nt][r] + bv;
      }
  }
  #undef GSTAGE
}

// ---------------------------------------------------------------------------
// MFMA flash attention v10: v7 minus V-staging — V read directly from
// L2-resident VT inside PV (loads consumed immediately: no prefetch array,
// no spill; different from R9's vr[14] and from R7's 72-VGPR-capped version).
// LDS = K dbuf 32K + P 18K = 50,176 B -> 3 blocks/CU (12 waves, +50% TLP to
// hide the exposed L2 latency). Everything else (paired q-blocks, static-m
// exp2 softmax, setprio, pre-swizzled K staging) identical to v7.
__global__ __launch_bounds__(256, 3) void attn_kernel(const bf16* __restrict__ Qp,
    const bf16* __restrict__ Kp, const bf16* __restrict__ VT, bf16* __restrict__ AOb){
  __shared__ __align__(16) char ktile[2][16384];
  __shared__ __align__(16) uint32 pshare[4*2*16*36];   // [wave][tile][q][36]
  const float NEGINF = -__builtin_inff();
  int bid = blockIdx.x;                          // 512 = 8 xcd x (16 pr x 4 bh)
  int xcd = bid & 7, idx = bid >> 3;             // idx 0..63
  int bh  = xcd*4 + (idx & 3);
  int pr  = idx >> 2;                            // 0..15
  int qbA = pr, qbB = 31 - pr;
  int tid = threadIdx.x;
  int w = tid >> 6, l = tid & 63;
  int g = l >> 4, qi = l & 15;
  int q0A = qbA*64 + w*16, q0B = qbB*64 + w*16;
  int nchA = qbA + 1, nchB = qbB + 1;

  const bf16* Qbase = Qp + (size_t)bh*T_*DP + g*8;
  const char* Kg    = (const char*)(Kp + (size_t)bh*T_*DP);
  const char* Vg    = (const char*)(VT + (size_t)bh*DP*T_);   // row d: 4096B stride

  short8 qfA[4], qfB[4];
  #pragma unroll
  for (int ks=0; ks<4; ++ks){
    qfA[ks] = *reinterpret_cast<const short8*>(Qbase + (size_t)(q0A + qi)*DP + ks*32);
    qfB[ks] = *reinterpret_cast<const short8*>(Qbase + (size_t)(q0B + qi)*DP + ks*32);
  }

  f32x4 accA[7], accB[7];
  #pragma unroll
  for (int dt=0; dt<7; ++dt){
    accA[dt] = (f32x4){0.f,0.f,0.f,0.f};
    accB[dt] = (f32x4){0.f,0.f,0.f,0.f};
  }
  float lrA = 0.f, lrB = 0.f;                    // lane-partial row sums

  uint32* pbB = &pshare[((w*2 + 0)*16 + qi)*36];
  uint32* pbA = &pshare[((w*2 + 1)*16 + qi)*36];

  // K: wave w stages rows [w*16, w*16+16): 4 x 64 lanes x 16B = 4KB
  int st_off0 = w*4096 + l*16;
  #define STAGE(J, BUF) { int k0s = (J) << 6;                                   \
    _Pragma("unroll")                                                           \
    for (int it=0; it<4; ++it){                                                 \
      int off = st_off0 + it*1024;                                              \
      int row = off >> 8;                                                       \
      int cb  = off & 255;                                                      \
      gl_lds16(Kg + (size_t)(k0s + row)*256 + (cb ^ ((row&15)<<4)),             \
               &ktile[BUF][w*4096 + it*1024]); } }

  // static-m softmax + pack for one tile (st -> pb)
  auto softpack = [&](const f32x4 st[4], float& lr, int qglob, int k0,
                      bool maskch, uint32* pb){
    float p[4][4];
    if (maskch){
      #pragma unroll
      for (int kt=0; kt<4; ++kt)
        #pragma unroll
        for (int r=0; r<4; ++r){
          int key = k0 + kt*16 + 4*g + r;
          float v = st[kt][r]; if (key > qglob) v = NEGINF;
          p[kt][r] = exp2f(v - MSTATIC);         // masked: exp2(-inf)=0
        }
    } else {
      #pragma unroll
      for (int kt=0; kt<4; ++kt)
        #pragma unroll
        for (int r=0; r<4; ++r)
          p[kt][r] = exp2f(st[kt][r] - MSTATIC);
    }
    float rs = 0.f;
    #pragma unroll
    for (int kt=0; kt<4; ++kt)
      #pragma unroll
      for (int r=0; r<4; ++r) rs += p[kt][r];
    lr += rs;                                    // lane-partial; reduce at end
    #pragma unroll
    for (int kt=0; kt<4; ++kt){
      pb[kt*8 + 2*g    ] = pk2(p[kt][0], p[kt][1]);
      pb[kt*8 + 2*g + 1] = pk2(p[kt][2], p[kt][3]);
    }
  };

  STAGE(0, 0)
  __syncthreads();

  for (int j = 0; j < nchB; ++j){
    int k0 = j << 6;
    int cur = j & 1;
    if (j + 1 < nchB) STAGE(j+1, cur^1)
    const char* kb = ktile[cur];
    bool dual = (j < nchA);
    // ---- QK: shared kf reads feed both tiles ----
    f32x4 stA[4], stB[4];
    __builtin_amdgcn_s_setprio(1);
    #pragma unroll
    for (int kt=0; kt<4; ++kt){
      f32x4 sB = (f32x4){0.f,0.f,0.f,0.f};
      f32x4 sA = (f32x4){0.f,0.f,0.f,0.f};
      #pragma unroll
      for (int ks=0; ks<4; ++ks){
        short8 kf = *reinterpret_cast<const short8*>(
            kb + (kt*16 + qi)*256 + ((ks*64 + g*16) ^ (qi<<4)));
        sB = __builtin_amdgcn_mfma_f32_16x16x32_bf16(kf, qfB[ks], sB, 0, 0, 0);
        if (dual)
          sA = __builtin_amdgcn_mfma_f32_16x16x32_bf16(kf, qfA[ks], sA, 0, 0, 0);
      }
      stB[kt] = sB; stA[kt] = sA;
    }
    __builtin_amdgcn_s_setprio(0);
    // ---- softmax + pack (no cross-lane ops) ----
    softpack(stB, lrB, q0B + qi, k0, j == nchB - 1, pbB);
    if (dual)
      softpack(stA, lrA, q0A + qi, k0, j == nchA - 1, pbA);
    // ---- PV: V direct from L2; vf feeds both tiles ----
    __builtin_amdgcn_s_setprio(1);
    #pragma unroll
    for (int ks=0; ks<2; ++ks){
      short8 paB = *reinterpret_cast<const short8*>(pbB + 16*ks + 4*g); // same-wave RAW
      short8 paA = *reinterpret_cast<const short8*>(pbA + 16*ks + 4*g);
      #pragma unroll
      for (int dt=0; dt<7; ++dt){
        short8 vf = *reinterpret_cast<const short8*>(
            Vg + (size_t)(dt*16 + qi)*(T_*2) + (size_t)(k0 + ks*32 + g*8)*2);
        accB[dt] = __builtin_amdgcn_mfma_f32_16x16x32_bf16(paB, vf, accB[dt], 0, 0, 0);
        if (dual)
          accA[dt] = __builtin_amdgcn_mfma_f32_16x16x32_bf16(paA, vf, accA[dt], 0, 0, 0);
      }
    }
    __builtin_amdgcn_s_setprio(0);
    __syncthreads();   // drains vmcnt (next K staged a full chunk ago)
  }

  // epilogue: reduce lr across the 4 g-groups (once, not per chunk)
  lrA += __shfl_xor(lrA, 16); lrA += __shfl_xor(lrA, 32);
  lrB += __shfl_xor(lrB, 16); lrB += __shfl_xor(lrB, 32);

  int b = bh >> 2, h = bh & 3;
  #pragma unroll
  for (int tix=0; tix<2; ++tix){
    f32x4* acc = tix ? accA : accB;
    float lr = tix ? lrA : lrB;
    int q0 = tix ? q0A : q0B;
    float inv = 1.f / lr;
    float invr[4];
    #pragma unroll
    for (int r=0; r<4; ++r) invr[r] = __shfl(inv, 20*g + r);
    #pragma unroll
    for (int dt=0; dt<7; ++dt){
      int d = dt*16 + qi;
      if (d < D_){
        #pragma unroll
        for (int r=0; r<4; ++r){
          size_t row = (size_t)(b*T_) + q0 + 4*g + r;
          AOb[row*KP + h*D_ + d] = f2bf(acc[dt][r] * invr[r]);
        }
      }
    }
  }
  #undef STAGE
}

// ---------------------------------------------------------------------------
extern "C" void kernel_launch(void* const* d_in, const int* in_sizes, int n_in,
                              void* d_out, int out_size, void* d_ws, size_t ws_size,
                              hipStream_t stream){
  const float* x  = (const float*)d_in[0];
  const float* Wq = (const float*)d_in[1];
  const float* Wk = (const float*)d_in[2];
  const float* Wv = (const float*)d_in[3];
  const float* Wo = (const float*)d_in[4];
  const float* bo = (const float*)d_in[5];

  constexpr size_t NBH  = (size_t)B_*H_;                 // 32
  constexpr size_t NPAD = NBH*T_*DP;                     // 8,388,608 elems
  constexpr size_t NROW = (size_t)B_*T_;                 // 16384
  constexpr size_t OFF_QP  = 0;
  constexpr size_t OFF_KP  = OFF_QP + NPAD*2;
  constexpr size_t OFF_VT  = OFF_KP + NPAD*2;
  constexpr size_t OFF_XB  = OFF_VT + NPAD*2;
  constexpr size_t OFF_AOB = OFF_XB + NROW*KP*2;
  constexpr size_t OFF_WT  = OFF_AOB + NROW*KP*2;
  constexpr size_t OFF_WOB = OFF_WT + (size_t)12*128*KP*2;
  constexpr size_t TOTAL   = OFF_WOB + (size_t)512*KP*2; // ~79.3 MB
  if (ws_size < TOTAL) return;   // visible failure signature (output stays zero)

  char* ws = (char*)d_ws;
  bf16*  Qp   = (bf16*)(ws + OFF_QP);
  bf16*  Kp   = (bf16*)(ws + OFF_KP);
  bf16*  VTp  = (bf16*)(ws + OFF_VT);
  bf16*  xb   = (bf16*)(ws + OFF_XB);
  bf16*  AOb  = (bf16*)(ws + OFF_AOB);
  bf16*  WT   = (bf16*)(ws + OFF_WT);
  bf16*  WoB  = (bf16*)(ws + OFF_WOB);
  float* out  = (float*)d_out;

  // prep domain: 16384*52 (x conv) + 12*128*416 (WT) + 512*416 (WoB)
  constexpr int PREP_N = 16384*52 + 12*128*KP + 512*KP;  // 1,703,936
  prep_all_kernel<<<(PREP_N + 255)/256, 256, 0, stream>>>(x, Wq, Wk, Wv, Wo, xb, WT, WoB);
  qkv_gemm_kernel<<<768, 256, 0, stream>>>(xb, WT, Qp, Kp, VTp);
  attn_kernel<<<512, 256, 0, stream>>>(Qp, Kp, VTp, AOb);
  out_gemm_kernel<<<512, 256, 0, stream>>>(AOb, WoB, bo, out);
}

// Round 17
// 141.705 us; speedup vs baseline: 1.8555x; 1.8555x over previous
//
#include <hip/hip_runtime.h>
#include <hip/hip_bf16.h>

#define B_ 8
#define T_ 2048
#define C_ 400
#define H_ 4
#define D_ 100
#define DP 128
#define KP 416   // C_ padded to 13*32
#define KPB 832  // KP bytes (bf16)
// Q prescale: 1/sqrt(100) * log2(e)  (softmax runs in exp2 domain)
#define QSCALE 0.14426950408889634f
// static softmax shift (shift-invariant; >=9-sigma bound on log2-domain scores)
#define MSTATIC 16.0f

typedef __hip_bfloat16 bf16;
typedef unsigned int uint32;
typedef __attribute__((ext_vector_type(8))) short short8;
typedef __attribute__((ext_vector_type(4))) float f32x4;

__device__ __forceinline__ float bf2f(bf16 v){ return __bfloat162float(v); }
__device__ __forceinline__ bf16 f2bf(float f){ return __float2bfloat16(f); }
__device__ __forceinline__ unsigned short bfbits(float f){
  bf16 h = f2bf(f);
  return __builtin_bit_cast(unsigned short, h);
}
__device__ __forceinline__ uint32 pk2(float a, float b){
  return (uint32)bfbits(a) | ((uint32)bfbits(b) << 16);
}
__device__ __forceinline__ void gl_lds16(const char* gsrc, char* ldst){
  __builtin_amdgcn_global_load_lds(
      (const __attribute__((address_space(1))) unsigned int*)gsrc,
      (__attribute__((address_space(3))) unsigned int*)ldst, 16, 0, 0);
}

// ---------------------------------------------------------------------------
// Merged cold prep (one launch):
//  [0, 16384*52)          : x fp32 -> xb bf16 [16384][416], pad cols zero
//  [.., +12*128*416)      : WT [12][128][416] = Wq/Wk/Wv transposed, padded
//  [.., +512*416)         : WoB [512][416] = Wo rows (W^T layout), padded
__global__ __launch_bounds__(256) void prep_all_kernel(const float* __restrict__ x,
    const float* __restrict__ Wq, const float* __restrict__ Wk,
    const float* __restrict__ Wv, const float* __restrict__ Wo,
    bf16* __restrict__ xb, bf16* __restrict__ WT, bf16* __restrict__ WoB){
  int i = blockIdx.x*256 + threadIdx.x;
  if (i < 16384*52){
    int c8 = i % 52, t = i / 52;
    uint32 u[4];
    if (c8 < 50){
      const float* src = x + (size_t)t*C_ + c8*8;
      #pragma unroll
      for (int k=0;k<4;++k) u[k] = pk2(src[2*k], src[2*k+1]);
    } else {
      u[0]=u[1]=u[2]=u[3]=0;
    }
    *reinterpret_cast<uint4*>((char*)xb + (size_t)t*KPB + c8*16) = make_uint4(u[0],u[1],u[2],u[3]);
    return;
  }
  i -= 16384*52;
  if (i < 12*128*KP){
    int c = i % KP, n = (i/KP) & 127, group = i/(KP*128);
    int p = group >> 2, h = group & 3;
    float v = 0.f;
    if (n < D_ && c < C_){
      const float* W = (p==0)?Wq:(p==1)?Wk:Wv;
      v = W[((size_t)h*C_ + c)*D_ + n];
    }
    WT[i] = f2bf(v);
    return;
  }
  i -= 12*128*KP;
  if (i < 512*KP){
    int c = i % KP, n = i / KP;
    float v = (n < C_ && c < C_) ? Wo[(size_t)n*C_ + c] : 0.f;
    WoB[i] = f2bf(v);
  }
}

// ---------------------------------------------------------------------------
// QKV MFMA GEMM: C = xb * WT_g^T per (p,h) group. Q stores pre-scaled by QSCALE.
__global__ __launch_bounds__(256) void qkv_gemm_kernel(const bf16* __restrict__ xb,
    const bf16* __restrict__ WT, bf16* __restrict__ Qp, bf16* __restrict__ Kp,
    bf16* __restrict__ VT){
  __shared__ __align__(16) char xs[2][8192];
  __shared__ __align__(16) char wsh[2][8192];
  int bid = blockIdx.x;
  int xcd = bid & 7, idx = bid >> 3;             // idx 0..191
  int mb = xcd*16 + idx/12;
  int group = idx % 12;
  int p = group >> 2, h = group & 3;
  int t0 = mb * 128;
  int tid = threadIdx.x;
  int w = tid >> 6, l = tid & 63, g = l >> 4, qi = l & 15;
  const char* xg = (const char*)xb + (size_t)t0*KPB;
  const char* wg = (const char*)WT + (size_t)group*128*KPB;
  int srow = tid >> 2, sseg = tid & 3;

  #define GSTAGE(J, BUF) {                                                     \
    int kc2 = (J)*64;                                                          \
    _Pragma("unroll")                                                          \
    for (int r2=0;r2<2;++r2)                                                   \
      gl_lds16(xg + (size_t)(srow + r2*64)*KPB + kc2 + sseg*16,                \
               &xs[BUF][tid*16 + r2*4096]);                                    \
    _Pragma("unroll")                                                          \
    for (int r2=0;r2<2;++r2)                                                   \
      gl_lds16(wg + (size_t)(srow + r2*64)*KPB + kc2 + sseg*16,                \
               &wsh[BUF][tid*16 + r2*4096]); }

  f32x4 acc[2][8];
  #pragma unroll
  for (int mt=0;mt<2;++mt)
    #pragma unroll
    for (int nt=0;nt<8;++nt) acc[mt][nt] = (f32x4){0.f,0.f,0.f,0.f};

  GSTAGE(0, 0)
  __syncthreads();
  for (int j = 0; j < 13; ++j){
    int cur = j & 1;
    if (j < 12) GSTAGE(j+1, cur^1)
    short8 af[2];
    #pragma unroll
    for (int mt=0;mt<2;++mt)
      af[mt] = *reinterpret_cast<const short8*>(&xs[cur][(w*32 + mt*16 + qi)*64 + g*16]);
    short8 bfr[8];
    #pragma unroll
    for (int nt=0;nt<8;++nt)
      bfr[nt] = *reinterpret_cast<const short8*>(&wsh[cur][(nt*16 + qi)*64 + g*16]);
    if (p < 2){
      #pragma unroll
      for (int mt=0;mt<2;++mt)
        #pragma unroll
        for (int nt=0;nt<8;++nt)
          acc[mt][nt] = __builtin_amdgcn_mfma_f32_16x16x32_bf16(af[mt], bfr[nt], acc[mt][nt], 0,0,0);
    } else {
      #pragma unroll
      for (int mt=0;mt<2;++mt)
        #pragma unroll
        for (int nt=0;nt<8;++nt)
          acc[mt][nt] = __builtin_amdgcn_mfma_f32_16x16x32_bf16(bfr[nt], af[mt], acc[mt][nt], 0,0,0);
    }
    __syncthreads();
  }

  int b = t0 >> 11, tloc0 = t0 & 2047;
  size_t bh = (size_t)b*H_ + h;
  if (p < 2){
    float qs = (p==0) ? QSCALE : 1.0f;
    bf16* dst = (p==0 ? Qp : Kp) + (bh*T_ + tloc0)*DP;
    #pragma unroll
    for (int mt=0;mt<2;++mt)
      #pragma unroll
      for (int r=0;r<4;++r){
        int tr = w*32 + mt*16 + 4*g + r;
        #pragma unroll
        for (int nt=0;nt<8;++nt)
          dst[(size_t)tr*DP + nt*16 + qi] = f2bf(qs * acc[mt][nt][r]);
      }
  } else {
    bf16* dstv = VT + bh*DP*T_ + tloc0;
    #pragma unroll
    for (int nt=0;nt<8;++nt)
      #pragma unroll
      for (int r=0;r<4;++r){
        int d = nt*16 + 4*g + r;
        #pragma unroll
        for (int mt=0;mt<2;++mt)
          dstv[(size_t)d*T_ + w*32 + mt*16 + qi] = f2bf(acc[mt][nt][r]);
      }
  }
  #undef GSTAGE
}

// ---------------------------------------------------------------------------
// Out-proj MFMA GEMM (unchanged).
__global__ __launch_bounds__(256) void out_gemm_kernel(const bf16* __restrict__ AOb,
    const bf16* __restrict__ WoB, const float* __restrict__ bo, float* __restrict__ out){
  __shared__ __align__(16) char xs[2][8192];
  __shared__ __align__(16) char wsh[2][8192];
  int bid = blockIdx.x;
  int xcd = bid & 7, idx = bid >> 3;             // idx 0..63
  int mb = xcd*16 + idx/4;
  int nb = idx & 3;
  int t0 = mb * 128, n0 = nb * 128;
  int tid = threadIdx.x;
  int w = tid >> 6, l = tid & 63, g = l >> 4, qi = l & 15;
  const char* xg = (const char*)AOb + (size_t)t0*KPB;
  const char* wg = (const char*)WoB + (size_t)n0*KPB;
  int srow = tid >> 2, sseg = tid & 3;

  #define GSTAGE(J, BUF) {                                                     \
    int kc2 = (J)*64;                                                          \
    _Pragma("unroll")                                                          \
    for (int r2=0;r2<2;++r2)                                                   \
      gl_lds16(xg + (size_t)(srow + r2*64)*KPB + kc2 + sseg*16,                \
               &xs[BUF][tid*16 + r2*4096]);                                    \
    _Pragma("unroll")                                                          \
    for (int r2=0;r2<2;++r2)                                                   \
      gl_lds16(wg + (size_t)(srow + r2*64)*KPB + kc2 + sseg*16,                \
               &wsh[BUF][tid*16 + r2*4096]); }

  f32x4 acc[2][8];
  #pragma unroll
  for (int mt=0;mt<2;++mt)
    #pragma unroll
    for (int nt=0;nt<8;++nt) acc[mt][nt] = (f32x4){0.f,0.f,0.f,0.f};

  GSTAGE(0, 0)
  __syncthreads();
  for (int j = 0; j < 13; ++j){
    int cur = j & 1;
    if (j < 12) GSTAGE(j+1, cur^1)
    short8 af[2];
    #pragma unroll
    for (int mt=0;mt<2;++mt)
      af[mt] = *reinterpret_cast<const short8*>(&xs[cur][(w*32 + mt*16 + qi)*64 + g*16]);
    short8 bfr[8];
    #pragma unroll
    for (int nt=0;nt<8;++nt)
      bfr[nt] = *reinterpret_cast<const short8*>(&wsh[cur][(nt*16 + qi)*64 + g*16]);
    #pragma unroll
    for (int mt=0;mt<2;++mt)
      #pragma unroll
      for (int nt=0;nt<8;++nt)
        acc[mt][nt] = __builtin_amdgcn_mfma_f32_16x16x32_bf16(af[mt], bfr[nt], acc[mt][nt], 0,0,0);
    __syncthreads();
  }

  #pragma unroll
  for (int nt=0;nt<8;++nt){
    if (n0 + nt*16 >= C_) continue;              // wave-uniform (400 % 16 == 0)
    int n = n0 + nt*16 + qi;
    float bv = bo[n];
    #pragma unroll
    for (int mt=0;mt<2;++mt)
      #pragma unroll
      for (int r=0;r<4;++r){
        int tr = w*32 + mt*16 + 4*g + r;
        out[(size_t)(t0 + tr)*C_ + n] = acc[mt][nt][r] + bv;
      }
  }
  #undef GSTAGE
}

// ---------------------------------------------------------------------------
// MFMA flash attention v7 (R12/R15 verbatim — best measured: 83 us).
// Paired q-blocks (uniform 33 chunk-works), K-tile + V-slab LDS-staged
// double-buffered via global_load_lds with pre-swizzled sources, stage at
// iter start -> full-iteration coverage before the single barrier drain,
// static-m exp2-domain softmax (no cross-lane ops in loop), setprio on MFMA.
__global__ __launch_bounds__(256, 2) void attn_kernel(const bf16* __restrict__ Qp,
    const bf16* __restrict__ Kp, const bf16* __restrict__ VT, bf16* __restrict__ AOb){
  __shared__ __align__(16) char ktile[2][16384];
  __shared__ __align__(16) char vtile[2][14336];
  __shared__ __align__(16) uint32 pshare[4*2*16*36];   // [wave][tile][q][36]
  const float NEGINF = -__builtin_inff();
  int bid = blockIdx.x;                          // 512 = 8 xcd x (16 pr x 4 bh)
  int xcd = bid & 7, idx = bid >> 3;             // idx 0..63
  int bh  = xcd*4 + (idx & 3);
  int pr  = idx >> 2;                            // 0..15
  int qbA = pr, qbB = 31 - pr;
  int tid = threadIdx.x;
  int w = tid >> 6, l = tid & 63;
  int g = l >> 4, qi = l & 15;
  int q0A = qbA*64 + w*16, q0B = qbB*64 + w*16;
  int nchA = qbA + 1, nchB = qbB + 1;

  const bf16* Qbase = Qp + (size_t)bh*T_*DP + g*8;
  const char* Kg    = (const char*)(Kp + (size_t)bh*T_*DP);
  const char* Vg    = (const char*)(VT + (size_t)bh*DP*T_);   // row d: 4096B stride

  short8 qfA[4], qfB[4];
  #pragma unroll
  for (int ks=0; ks<4; ++ks){
    qfA[ks] = *reinterpret_cast<const short8*>(Qbase + (size_t)(q0A + qi)*DP + ks*32);
    qfB[ks] = *reinterpret_cast<const short8*>(Qbase + (size_t)(q0B + qi)*DP + ks*32);
  }

  f32x4 accA[7], accB[7];
  #pragma unroll
  for (int dt=0; dt<7; ++dt){
    accA[dt] = (f32x4){0.f,0.f,0.f,0.f};
    accB[dt] = (f32x4){0.f,0.f,0.f,0.f};
  }
  float lrA = 0.f, lrB = 0.f;                    // lane-partial row sums

  uint32* pbB = &pshare[((w*2 + 0)*16 + qi)*36];
  uint32* pbA = &pshare[((w*2 + 1)*16 + qi)*36];

  // K: wave w stages rows [w*16, w*16+16): 4 x 64 lanes x 16B = 4KB
  int st_off0 = w*4096 + l*16;
  #define STAGE(J, BUF) { int k0s = (J) << 6;                                   \
    _Pragma("unroll")                                                           \
    for (int it=0; it<4; ++it){                                                 \
      int off = st_off0 + it*1024;                                              \
      int row = off >> 8;                                                       \
      int cb  = off & 255;                                                      \
      gl_lds16(Kg + (size_t)(k0s + row)*256 + (cb ^ ((row&15)<<4)),             \
               &ktile[BUF][w*4096 + it*1024]); } }

  // V: slab rows d=0..111 (128B each), 14 issues round-robined over waves.
  #define VSTAGE(J, BUF) { int k0s2 = ((J) << 6)*2;                             \
    for (int it=w; it<14; it+=4){                                               \
      int off = it*1024 + l*16;                                                 \
      int row = off >> 7;                                                       \
      int cb  = off & 127;                                                      \
      gl_lds16(Vg + (size_t)row*(T_*2) + k0s2 + (cb ^ ((row&7)<<4)),            \
               &vtile[BUF][it*1024 + l*16]); } }

  // static-m softmax + pack for one tile (st -> pb)
  auto softpack = [&](const f32x4 st[4], float& lr, int qglob, int k0,
                      bool maskch, uint32* pb){
    float p[4][4];
    if (maskch){
      #pragma unroll
      for (int kt=0; kt<4; ++kt)
        #pragma unroll
        for (int r=0; r<4; ++r){
          int key = k0 + kt*16 + 4*g + r;
          float v = st[kt][r]; if (key > qglob) v = NEGINF;
          p[kt][r] = exp2f(v - MSTATIC);         // masked: exp2(-inf)=0
        }
    } else {
      #pragma unroll
      for (int kt=0; kt<4; ++kt)
        #pragma unroll
        for (int r=0; r<4; ++r)
          p[kt][r] = exp2f(st[kt][r] - MSTATIC);
    }
    float rs = 0.f;
    #pragma unroll
    for (int kt=0; kt<4; ++kt)
      #pragma unroll
      for (int r=0; r<4; ++r) rs += p[kt][r];
    lr += rs;                                    // lane-partial; reduce at end
    #pragma unroll
    for (int kt=0; kt<4; ++kt){
      pb[kt*8 + 2*g    ] = pk2(p[kt][0], p[kt][1]);
      pb[kt*8 + 2*g + 1] = pk2(p[kt][2], p[kt][3]);
    }
  };

  STAGE(0, 0)
  VSTAGE(0, 0)
  __syncthreads();

  for (int j = 0; j < nchB; ++j){
    int k0 = j << 6;
    int cur = j & 1;
    if (j + 1 < nchB){ STAGE(j+1, cur^1) VSTAGE(j+1, cur^1) }
    const char* kb = ktile[cur];
    const char* vb = vtile[cur];
    bool dual = (j < nchA);
    // ---- QK: shared kf reads feed both tiles ----
    f32x4 stA[4], stB[4];
    __builtin_amdgcn_s_setprio(1);
    #pragma unroll
    for (int kt=0; kt<4; ++kt){
      f32x4 sB = (f32x4){0.f,0.f,0.f,0.f};
      f32x4 sA = (f32x4){0.f,0.f,0.f,0.f};
      #pragma unroll
      for (int ks=0; ks<4; ++ks){
        short8 kf = *reinterpret_cast<const short8*>(
            kb + (kt*16 + qi)*256 + ((ks*64 + g*16) ^ (qi<<4)));
        sB = __builtin_amdgcn_mfma_f32_16x16x32_bf16(kf, qfB[ks], sB, 0, 0, 0);
        if (dual)
          sA = __builtin_amdgcn_mfma_f32_16x16x32_bf16(kf, qfA[ks], sA, 0, 0, 0);
      }
      stB[kt] = sB; stA[kt] = sA;
    }
    __builtin_amdgcn_s_setprio(0);
    // ---- softmax + pack (no cross-lane ops) ----
    softpack(stB, lrB, q0B + qi, k0, j == nchB - 1, pbB);
    if (dual)
      softpack(stA, lrA, q0A + qi, k0, j == nchA - 1, pbA);
    // ---- PV: shared vf reads feed both tiles ----
    __builtin_amdgcn_s_setprio(1);
    #pragma unroll
    for (int ks=0; ks<2; ++ks){
      short8 paB = *reinterpret_cast<const short8*>(pbB + 16*ks + 4*g); // same-wave RAW
      short8 paA = *reinterpret_cast<const short8*>(pbA + 16*ks + 4*g);
      #pragma unroll
      for (int dt=0; dt<7; ++dt){
        int row = dt*16 + qi;
        short8 vf = *reinterpret_cast<const short8*>(
            vb + row*128 + ((ks*64 + g*16) ^ ((qi&7)<<4)));
        accB[dt] = __builtin_amdgcn_mfma_f32_16x16x32_bf16(paB, vf, accB[dt], 0, 0, 0);
        if (dual)
          accA[dt] = __builtin_amdgcn_mfma_f32_16x16x32_bf16(paA, vf, accA[dt], 0, 0, 0);
      }
    }
    __builtin_amdgcn_s_setprio(0);
    __syncthreads();   // drains vmcnt (next K+V staged a full chunk ago)
  }

  // epilogue: reduce lr across the 4 g-groups (once, not per chunk)
  lrA += __shfl_xor(lrA, 16); lrA += __shfl_xor(lrA, 32);
  lrB += __shfl_xor(lrB, 16); lrB += __shfl_xor(lrB, 32);

  int b = bh >> 2, h = bh & 3;
  #pragma unroll
  for (int tix=0; tix<2; ++tix){
    f32x4* acc = tix ? accA : accB;
    float lr = tix ? lrA : lrB;
    int q0 = tix ? q0A : q0B;
    float inv = 1.f / lr;
    float invr[4];
    #pragma unroll
    for (int r=0; r<4; ++r) invr[r] = __shfl(inv, 20*g + r);
    #pragma unroll
    for (int dt=0; dt<7; ++dt){
      int d = dt*16 + qi;
      if (d < D_){
        #pragma unroll
        for (int r=0; r<4; ++r){
          size_t row = (size_t)(b*T_) + q0 + 4*g + r;
          AOb[row*KP + h*D_ + d] = f2bf(acc[dt][r] * invr[r]);
        }
      }
    }
  }
  #undef STAGE
  #undef VSTAGE
}

// ---------------------------------------------------------------------------
extern "C" void kernel_launch(void* const* d_in, const int* in_sizes, int n_in,
                              void* d_out, int out_size, void* d_ws, size_t ws_size,
                              hipStream_t stream){
  const float* x  = (const float*)d_in[0];
  const float* Wq = (const float*)d_in[1];
  const float* Wk = (const float*)d_in[2];
  const float* Wv = (const float*)d_in[3];
  const float* Wo = (const float*)d_in[4];
  const float* bo = (const float*)d_in[5];

  constexpr size_t NBH  = (size_t)B_*H_;                 // 32
  constexpr size_t NPAD = NBH*T_*DP;                     // 8,388,608 elems
  constexpr size_t NROW = (size_t)B_*T_;                 // 16384
  constexpr size_t OFF_QP  = 0;
  constexpr size_t OFF_KP  = OFF_QP + NPAD*2;
  constexpr size_t OFF_VT  = OFF_KP + NPAD*2;
  constexpr size_t OFF_XB  = OFF_VT + NPAD*2;
  constexpr size_t OFF_AOB = OFF_XB + NROW*KP*2;
  constexpr size_t OFF_WT  = OFF_AOB + NROW*KP*2;
  constexpr size_t OFF_WOB = OFF_WT + (size_t)12*128*KP*2;
  constexpr size_t TOTAL   = OFF_WOB + (size_t)512*KP*2; // ~79.3 MB
  if (ws_size < TOTAL) return;   // visible failure signature (output stays zero)

  char* ws = (char*)d_ws;
  bf16*  Qp   = (bf16*)(ws + OFF_QP);
  bf16*  Kp   = (bf16*)(ws + OFF_KP);
  bf16*  VTp  = (bf16*)(ws + OFF_VT);
  bf16*  xb   = (bf16*)(ws + OFF_XB);
  bf16*  AOb  = (bf16*)(ws + OFF_AOB);
  bf16*  WT   = (bf16*)(ws + OFF_WT);
  bf16*  WoB  = (bf16*)(ws + OFF_WOB);
  float* out  = (float*)d_out;

  // prep domain: 16384*52 (x conv) + 12*128*416 (WT) + 512*416 (WoB)
  constexpr int PREP_N = 16384*52 + 12*128*KP + 512*KP;  // 1,703,936
  prep_all_kernel<<<(PREP_N + 255)/256, 256, 0, stream>>>(x, Wq, Wk, Wv, Wo, xb, WT, WoB);
  qkv_gemm_kernel<<<1536, 256, 0, stream>>>(xb, WT, Qp, Kp, VTp);
  attn_kernel<<<512, 256, 0, stream>>>(Qp, Kp, VTp, AOb);
  out_gemm_kernel<<<512, 256, 0, stream>>>(AOb, WoB, bo, out);
}

// Round 18
// 140.623 us; speedup vs baseline: 1.8697x; 1.0077x over previous
//
#include <hip/hip_runtime.h>
#include <hip/hip_bf16.h>

#define B_ 8
#define T_ 2048
#define C_ 400
#define H_ 4
#define D_ 100
#define DP 128
#define KP 416   // C_ padded to 13*32
#define KPB 832  // KP bytes (bf16)
// Q prescale: 1/sqrt(100) * log2(e)  (softmax runs in exp2 domain)
#define QSCALE 0.14426950408889634f
// static softmax shift (shift-invariant; >=9-sigma bound on log2-domain scores)
#define MSTATIC 16.0f

typedef __hip_bfloat16 bf16;
typedef unsigned int uint32;
typedef __attribute__((ext_vector_type(8))) short short8;
typedef __attribute__((ext_vector_type(4))) float f32x4;

__device__ __forceinline__ float bf2f(bf16 v){ return __bfloat162float(v); }
__device__ __forceinline__ bf16 f2bf(float f){ return __float2bfloat16(f); }
__device__ __forceinline__ unsigned short bfbits(float f){
  bf16 h = f2bf(f);
  return __builtin_bit_cast(unsigned short, h);
}
__device__ __forceinline__ uint32 pk2(float a, float b){
  return (uint32)bfbits(a) | ((uint32)bfbits(b) << 16);
}
// HW packed f32x2 -> bf16x2 (gfx950; no builtin — inline asm, T12/m214v22).
// dst.lo = cvt(a), dst.hi = cvt(b): drop-in for pk2. Register-only asm:
// data deps via operands -> no ordering hazard (rule #18 n/a).
__device__ __forceinline__ uint32 pk2f(float a, float b){
  uint32 r;
  asm("v_cvt_pk_bf16_f32 %0, %1, %2" : "=v"(r) : "v"(a), "v"(b));
  return r;
}
__device__ __forceinline__ void gl_lds16(const char* gsrc, char* ldst){
  __builtin_amdgcn_global_load_lds(
      (const __attribute__((address_space(1))) unsigned int*)gsrc,
      (__attribute__((address_space(3))) unsigned int*)ldst, 16, 0, 0);
}

// ---------------------------------------------------------------------------
// Merged cold prep (one launch):
//  [0, 16384*52)          : x fp32 -> xb bf16 [16384][416], pad cols zero
//  [.., +12*128*416)      : WT [12][128][416] = Wq/Wk/Wv transposed, padded
//  [.., +512*416)         : WoB [512][416] = Wo rows (W^T layout), padded
__global__ __launch_bounds__(256) void prep_all_kernel(const float* __restrict__ x,
    const float* __restrict__ Wq, const float* __restrict__ Wk,
    const float* __restrict__ Wv, const float* __restrict__ Wo,
    bf16* __restrict__ xb, bf16* __restrict__ WT, bf16* __restrict__ WoB){
  int i = blockIdx.x*256 + threadIdx.x;
  if (i < 16384*52){
    int c8 = i % 52, t = i / 52;
    uint32 u[4];
    if (c8 < 50){
      const float* src = x + (size_t)t*C_ + c8*8;
      #pragma unroll
      for (int k=0;k<4;++k) u[k] = pk2(src[2*k], src[2*k+1]);
    } else {
      u[0]=u[1]=u[2]=u[3]=0;
    }
    *reinterpret_cast<uint4*>((char*)xb + (size_t)t*KPB + c8*16) = make_uint4(u[0],u[1],u[2],u[3]);
    return;
  }
  i -= 16384*52;
  if (i < 12*128*KP){
    int c = i % KP, n = (i/KP) & 127, group = i/(KP*128);
    int p = group >> 2, h = group & 3;
    float v = 0.f;
    if (n < D_ && c < C_){
      const float* W = (p==0)?Wq:(p==1)?Wk:Wv;
      v = W[((size_t)h*C_ + c)*D_ + n];
    }
    WT[i] = f2bf(v);
    return;
  }
  i -= 12*128*KP;
  if (i < 512*KP){
    int c = i % KP, n = i / KP;
    float v = (n < C_ && c < C_) ? Wo[(size_t)n*C_ + c] : 0.f;
    WoB[i] = f2bf(v);
  }
}

// ---------------------------------------------------------------------------
// QKV MFMA GEMM: C = xb * WT_g^T per (p,h) group. Q stores pre-scaled by QSCALE.
__global__ __launch_bounds__(256) void qkv_gemm_kernel(const bf16* __restrict__ xb,
    const bf16* __restrict__ WT, bf16* __restrict__ Qp, bf16* __restrict__ Kp,
    bf16* __restrict__ VT){
  __shared__ __align__(16) char xs[2][8192];
  __shared__ __align__(16) char wsh[2][8192];
  int bid = blockIdx.x;
  int xcd = bid & 7, idx = bid >> 3;             // idx 0..191
  int mb = xcd*16 + idx/12;
  int group = idx % 12;
  int p = group >> 2, h = group & 3;
  int t0 = mb * 128;
  int tid = threadIdx.x;
  int w = tid >> 6, l = tid & 63, g = l >> 4, qi = l & 15;
  const char* xg = (const char*)xb + (size_t)t0*KPB;
  const char* wg = (const char*)WT + (size_t)group*128*KPB;
  int srow = tid >> 2, sseg = tid & 3;

  #define GSTAGE(J, BUF) {                                                     \
    int kc2 = (J)*64;                                                          \
    _Pragma("unroll")                                                          \
    for (int r2=0;r2<2;++r2)                                                   \
      gl_lds16(xg + (size_t)(srow + r2*64)*KPB + kc2 + sseg*16,                \
               &xs[BUF][tid*16 + r2*4096]);                                    \
    _Pragma("unroll")                                                          \
    for (int r2=0;r2<2;++r2)                                                   \
      gl_lds16(wg + (size_t)(srow + r2*64)*KPB + kc2 + sseg*16,                \
               &wsh[BUF][tid*16 + r2*4096]); }

  f32x4 acc[2][8];
  #pragma unroll
  for (int mt=0;mt<2;++mt)
    #pragma unroll
    for (int nt=0;nt<8;++nt) acc[mt][nt] = (f32x4){0.f,0.f,0.f,0.f};

  GSTAGE(0, 0)
  __syncthreads();
  for (int j = 0; j < 13; ++j){
    int cur = j & 1;
    if (j < 12) GSTAGE(j+1, cur^1)
    short8 af[2];
    #pragma unroll
    for (int mt=0;mt<2;++mt)
      af[mt] = *reinterpret_cast<const short8*>(&xs[cur][(w*32 + mt*16 + qi)*64 + g*16]);
    short8 bfr[8];
    #pragma unroll
    for (int nt=0;nt<8;++nt)
      bfr[nt] = *reinterpret_cast<const short8*>(&wsh[cur][(nt*16 + qi)*64 + g*16]);
    if (p < 2){
      #pragma unroll
      for (int mt=0;mt<2;++mt)
        #pragma unroll
        for (int nt=0;nt<8;++nt)
          acc[mt][nt] = __builtin_amdgcn_mfma_f32_16x16x32_bf16(af[mt], bfr[nt], acc[mt][nt], 0,0,0);
    } else {
      #pragma unroll
      for (int mt=0;mt<2;++mt)
        #pragma unroll
        for (int nt=0;nt<8;++nt)
          acc[mt][nt] = __builtin_amdgcn_mfma_f32_16x16x32_bf16(bfr[nt], af[mt], acc[mt][nt], 0,0,0);
    }
    __syncthreads();
  }

  int b = t0 >> 11, tloc0 = t0 & 2047;
  size_t bh = (size_t)b*H_ + h;
  if (p < 2){
    float qs = (p==0) ? QSCALE : 1.0f;
    bf16* dst = (p==0 ? Qp : Kp) + (bh*T_ + tloc0)*DP;
    #pragma unroll
    for (int mt=0;mt<2;++mt)
      #pragma unroll
      for (int r=0;r<4;++r){
        int tr = w*32 + mt*16 + 4*g + r;
        #pragma unroll
        for (int nt=0;nt<8;++nt)
          dst[(size_t)tr*DP + nt*16 + qi] = f2bf(qs * acc[mt][nt][r]);
      }
  } else {
    bf16* dstv = VT + bh*DP*T_ + tloc0;
    #pragma unroll
    for (int nt=0;nt<8;++nt)
      #pragma unroll
      for (int r=0;r<4;++r){
        int d = nt*16 + 4*g + r;
        #pragma unroll
        for (int mt=0;mt<2;++mt)
          dstv[(size_t)d*T_ + w*32 + mt*16 + qi] = f2bf(acc[mt][nt][r]);
      }
  }
  #undef GSTAGE
}

// ---------------------------------------------------------------------------
// Out-proj MFMA GEMM (unchanged).
__global__ __launch_bounds__(256) void out_gemm_kernel(const bf16* __restrict__ AOb,
    const bf16* __restrict__ WoB, const float* __restrict__ bo, float* __restrict__ out){
  __shared__ __align__(16) char xs[2][8192];
  __shared__ __align__(16) char wsh[2][8192];
  int bid = blockIdx.x;
  int xcd = bid & 7, idx = bid >> 3;             // idx 0..63
  int mb = xcd*16 + idx/4;
  int nb = idx & 3;
  int t0 = mb * 128, n0 = nb * 128;
  int tid = threadIdx.x;
  int w = tid >> 6, l = tid & 63, g = l >> 4, qi = l & 15;
  const char* xg = (const char*)AOb + (size_t)t0*KPB;
  const char* wg = (const char*)WoB + (size_t)n0*KPB;
  int srow = tid >> 2, sseg = tid & 3;

  #define GSTAGE(J, BUF) {                                                     \
    int kc2 = (J)*64;                                                          \
    _Pragma("unroll")                                                          \
    for (int r2=0;r2<2;++r2)                                                   \
      gl_lds16(xg + (size_t)(srow + r2*64)*KPB + kc2 + sseg*16,                \
               &xs[BUF][tid*16 + r2*4096]);                                    \
    _Pragma("unroll")                                                          \
    for (int r2=0;r2<2;++r2)                                                   \
      gl_lds16(wg + (size_t)(srow + r2*64)*KPB + kc2 + sseg*16,                \
               &wsh[BUF][tid*16 + r2*4096]); }

  f32x4 acc[2][8];
  #pragma unroll
  for (int mt=0;mt<2;++mt)
    #pragma unroll
    for (int nt=0;nt<8;++nt) acc[mt][nt] = (f32x4){0.f,0.f,0.f,0.f};

  GSTAGE(0, 0)
  __syncthreads();
  for (int j = 0; j < 13; ++j){
    int cur = j & 1;
    if (j < 12) GSTAGE(j+1, cur^1)
    short8 af[2];
    #pragma unroll
    for (int mt=0;mt<2;++mt)
      af[mt] = *reinterpret_cast<const short8*>(&xs[cur][(w*32 + mt*16 + qi)*64 + g*16]);
    short8 bfr[8];
    #pragma unroll
    for (int nt=0;nt<8;++nt)
      bfr[nt] = *reinterpret_cast<const short8*>(&wsh[cur][(nt*16 + qi)*64 + g*16]);
    #pragma unroll
    for (int mt=0;mt<2;++mt)
      #pragma unroll
      for (int nt=0;nt<8;++nt)
        acc[mt][nt] = __builtin_amdgcn_mfma_f32_16x16x32_bf16(af[mt], bfr[nt], acc[mt][nt], 0,0,0);
    __syncthreads();
  }

  #pragma unroll
  for (int nt=0;nt<8;++nt){
    if (n0 + nt*16 >= C_) continue;              // wave-uniform (400 % 16 == 0)
    int n = n0 + nt*16 + qi;
    float bv = bo[n];
    #pragma unroll
    for (int mt=0;mt<2;++mt)
      #pragma unroll
      for (int r=0;r<4;++r){
        int tr = w*32 + mt*16 + 4*g + r;
        out[(size_t)(t0 + tr)*C_ + n] = acc[mt][nt][r] + bv;
      }
  }
  #undef GSTAGE
}

// ---------------------------------------------------------------------------
// MFMA flash attention v7.1: R15/R17's v7 with ONE change — the P->bf16 pack
// uses HW v_cvt_pk_bf16_f32 (pk2f) instead of the ~5-op software RNE pair.
// Cuts ~80 VALU ops/tile-chunk to ~8 in softpack (VALUBusy was 35%).
__global__ __launch_bounds__(256, 2) void attn_kernel(const bf16* __restrict__ Qp,
    const bf16* __restrict__ Kp, const bf16* __restrict__ VT, bf16* __restrict__ AOb){
  __shared__ __align__(16) char ktile[2][16384];
  __shared__ __align__(16) char vtile[2][14336];
  __shared__ __align__(16) uint32 pshare[4*2*16*36];   // [wave][tile][q][36]
  const float NEGINF = -__builtin_inff();
  int bid = blockIdx.x;                          // 512 = 8 xcd x (16 pr x 4 bh)
  int xcd = bid & 7, idx = bid >> 3;             // idx 0..63
  int bh  = xcd*4 + (idx & 3);
  int pr  = idx >> 2;                            // 0..15
  int qbA = pr, qbB = 31 - pr;
  int tid = threadIdx.x;
  int w = tid >> 6, l = tid & 63;
  int g = l >> 4, qi = l & 15;
  int q0A = qbA*64 + w*16, q0B = qbB*64 + w*16;
  int nchA = qbA + 1, nchB = qbB + 1;

  const bf16* Qbase = Qp + (size_t)bh*T_*DP + g*8;
  const char* Kg    = (const char*)(Kp + (size_t)bh*T_*DP);
  const char* Vg    = (const char*)(VT + (size_t)bh*DP*T_);   // row d: 4096B stride

  short8 qfA[4], qfB[4];
  #pragma unroll
  for (int ks=0; ks<4; ++ks){
    qfA[ks] = *reinterpret_cast<const short8*>(Qbase + (size_t)(q0A + qi)*DP + ks*32);
    qfB[ks] = *reinterpret_cast<const short8*>(Qbase + (size_t)(q0B + qi)*DP + ks*32);
  }

  f32x4 accA[7], accB[7];
  #pragma unroll
  for (int dt=0; dt<7; ++dt){
    accA[dt] = (f32x4){0.f,0.f,0.f,0.f};
    accB[dt] = (f32x4){0.f,0.f,0.f,0.f};
  }
  float lrA = 0.f, lrB = 0.f;                    // lane-partial row sums

  uint32* pbB = &pshare[((w*2 + 0)*16 + qi)*36];
  uint32* pbA = &pshare[((w*2 + 1)*16 + qi)*36];

  // K: wave w stages rows [w*16, w*16+16): 4 x 64 lanes x 16B = 4KB
  int st_off0 = w*4096 + l*16;
  #define STAGE(J, BUF) { int k0s = (J) << 6;                                   \
    _Pragma("unroll")                                                           \
    for (int it=0; it<4; ++it){                                                 \
      int off = st_off0 + it*1024;                                              \
      int row = off >> 8;                                                       \
      int cb  = off & 255;                                                      \
      gl_lds16(Kg + (size_t)(k0s + row)*256 + (cb ^ ((row&15)<<4)),             \
               &ktile[BUF][w*4096 + it*1024]); } }

  // V: slab rows d=0..111 (128B each), 14 issues round-robined over waves.
  #define VSTAGE(J, BUF) { int k0s2 = ((J) << 6)*2;                             \
    for (int it=w; it<14; it+=4){                                               \
      int off = it*1024 + l*16;                                                 \
      int row = off >> 7;                                                       \
      int cb  = off & 127;                                                      \
      gl_lds16(Vg + (size_t)row*(T_*2) + k0s2 + (cb ^ ((row&7)<<4)),            \
               &vtile[BUF][it*1024 + l*16]); } }

  // static-m softmax + pack for one tile (st -> pb)
  auto softpack = [&](const f32x4 st[4], float& lr, int qglob, int k0,
                      bool maskch, uint32* pb){
    float p[4][4];
    if (maskch){
      #pragma unroll
      for (int kt=0; kt<4; ++kt)
        #pragma unroll
        for (int r=0; r<4; ++r){
          int key = k0 + kt*16 + 4*g + r;
          float v = st[kt][r]; if (key > qglob) v = NEGINF;
          p[kt][r] = exp2f(v - MSTATIC);         // masked: exp2(-inf)=0
        }
    } else {
      #pragma unroll
      for (int kt=0; kt<4; ++kt)
        #pragma unroll
        for (int r=0; r<4; ++r)
          p[kt][r] = exp2f(st[kt][r] - MSTATIC);
    }
    float rs = 0.f;
    #pragma unroll
    for (int kt=0; kt<4; ++kt)
      #pragma unroll
      for (int r=0; r<4; ++r) rs += p[kt][r];
    lr += rs;                                    // lane-partial; reduce at end
    #pragma unroll
    for (int kt=0; kt<4; ++kt){
      pb[kt*8 + 2*g    ] = pk2f(p[kt][0], p[kt][1]);
      pb[kt*8 + 2*g + 1] = pk2f(p[kt][2], p[kt][3]);
    }
  };

  STAGE(0, 0)
  VSTAGE(0, 0)
  __syncthreads();

  for (int j = 0; j < nchB; ++j){
    int k0 = j << 6;
    int cur = j & 1;
    if (j + 1 < nchB){ STAGE(j+1, cur^1) VSTAGE(j+1, cur^1) }
    const char* kb = ktile[cur];
    const char* vb = vtile[cur];
    bool dual = (j < nchA);
    // ---- QK: shared kf reads feed both tiles ----
    f32x4 stA[4], stB[4];
    __builtin_amdgcn_s_setprio(1);
    #pragma unroll
    for (int kt=0; kt<4; ++kt){
      f32x4 sB = (f32x4){0.f,0.f,0.f,0.f};
      f32x4 sA = (f32x4){0.f,0.f,0.f,0.f};
      #pragma unroll
      for (int ks=0; ks<4; ++ks){
        short8 kf = *reinterpret_cast<const short8*>(
            kb + (kt*16 + qi)*256 + ((ks*64 + g*16) ^ (qi<<4)));
        sB = __builtin_amdgcn_mfma_f32_16x16x32_bf16(kf, qfB[ks], sB, 0, 0, 0);
        if (dual)
          sA = __builtin_amdgcn_mfma_f32_16x16x32_bf16(kf, qfA[ks], sA, 0, 0, 0);
      }
      stB[kt] = sB; stA[kt] = sA;
    }
    __builtin_amdgcn_s_setprio(0);
    // ---- softmax + pack (no cross-lane ops) ----
    softpack(stB, lrB, q0B + qi, k0, j == nchB - 1, pbB);
    if (dual)
      softpack(stA, lrA, q0A + qi, k0, j == nchA - 1, pbA);
    // ---- PV: shared vf reads feed both tiles ----
    __builtin_amdgcn_s_setprio(1);
    #pragma unroll
    for (int ks=0; ks<2; ++ks){
      short8 paB = *reinterpret_cast<const short8*>(pbB + 16*ks + 4*g); // same-wave RAW
      short8 paA = *reinterpret_cast<const short8*>(pbA + 16*ks + 4*g);
      #pragma unroll
      for (int dt=0; dt<7; ++dt){
        int row = dt*16 + qi;
        short8 vf = *reinterpret_cast<const short8*>(
            vb + row*128 + ((ks*64 + g*16) ^ ((qi&7)<<4)));
        accB[dt] = __builtin_amdgcn_mfma_f32_16x16x32_bf16(paB, vf, accB[dt], 0, 0, 0);
        if (dual)
          accA[dt] = __builtin_amdgcn_mfma_f32_16x16x32_bf16(paA, vf, accA[dt], 0, 0, 0);
      }
    }
    __builtin_amdgcn_s_setprio(0);
    __syncthreads();   // drains vmcnt (next K+V staged a full chunk ago)
  }

  // epilogue: reduce lr across the 4 g-groups (once, not per chunk)
  lrA += __shfl_xor(lrA, 16); lrA += __shfl_xor(lrA, 32);
  lrB += __shfl_xor(lrB, 16); lrB += __shfl_xor(lrB, 32);

  int b = bh >> 2, h = bh & 3;
  #pragma unroll
  for (int tix=0; tix<2; ++tix){
    f32x4* acc = tix ? accA : accB;
    float lr = tix ? lrA : lrB;
    int q0 = tix ? q0A : q0B;
    float inv = 1.f / lr;
    float invr[4];
    #pragma unroll
    for (int r=0; r<4; ++r) invr[r] = __shfl(inv, 20*g + r);
    #pragma unroll
    for (int dt=0; dt<7; ++dt){
      int d = dt*16 + qi;
      if (d < D_){
        #pragma unroll
        for (int r=0; r<4; ++r){
          size_t row = (size_t)(b*T_) + q0 + 4*g + r;
          AOb[row*KP + h*D_ + d] = f2bf(acc[dt][r] * invr[r]);
        }
      }
    }
  }
  #undef STAGE
  #undef VSTAGE
}

// ---------------------------------------------------------------------------
extern "C" void kernel_launch(void* const* d_in, const int* in_sizes, int n_in,
                              void* d_out, int out_size, void* d_ws, size_t ws_size,
                              hipStream_t stream){
  const float* x  = (const float*)d_in[0];
  const float* Wq = (const float*)d_in[1];
  const float* Wk = (const float*)d_in[2];
  const float* Wv = (const float*)d_in[3];
  const float* Wo = (const float*)d_in[4];
  const float* bo = (const float*)d_in[5];

  constexpr size_t NBH  = (size_t)B_*H_;                 // 32
  constexpr size_t NPAD = NBH*T_*DP;                     // 8,388,608 elems
  constexpr size_t NROW = (size_t)B_*T_;                 // 16384
  constexpr size_t OFF_QP  = 0;
  constexpr size_t OFF_KP  = OFF_QP + NPAD*2;
  constexpr size_t OFF_VT  = OFF_KP + NPAD*2;
  constexpr size_t OFF_XB  = OFF_VT + NPAD*2;
  constexpr size_t OFF_AOB = OFF_XB + NROW*KP*2;
  constexpr size_t OFF_WT  = OFF_AOB + NROW*KP*2;
  constexpr size_t OFF_WOB = OFF_WT + (size_t)12*128*KP*2;
  constexpr size_t TOTAL   = OFF_WOB + (size_t)512*KP*2; // ~79.3 MB
  if (ws_size < TOTAL) return;   // visible failure signature (output stays zero)

  char* ws = (char*)d_ws;
  bf16*  Qp   = (bf16*)(ws + OFF_QP);
  bf16*  Kp   = (bf16*)(ws + OFF_KP);
  bf16*  VTp  = (bf16*)(ws + OFF_VT);
  bf16*  xb   = (bf16*)(ws + OFF_XB);
  bf16*  AOb  = (bf16*)(ws + OFF_AOB);
  bf16*  WT   = (bf16*)(ws + OFF_WT);
  bf16*  WoB  = (bf16*)(ws + OFF_WOB);
  float* out  = (float*)d_out;

  // prep domain: 16384*52 (x conv) + 12*128*416 (WT) + 512*416 (WoB)
  constexpr int PREP_N = 16384*52 + 12*128*KP + 512*KP;  // 1,703,936
  prep_all_kernel<<<(PREP_N + 255)/256, 256, 0, stream>>>(x, Wq, Wk, Wv, Wo, xb, WT, WoB);
  qkv_gemm_kernel<<<1536, 256, 0, stream>>>(xb, WT, Qp, Kp, VTp);
  attn_kernel<<<512, 256, 0, stream>>>(Qp, Kp, VTp, AOb);
  out_gemm_kernel<<<512, 256, 0, stream>>>(AOb, WoB, bo, out);
}